// Round 3
// 15228.592 us; speedup vs baseline: 1.0708x; 1.0708x over previous
//
#include <hip/hip_runtime.h>
#include <hip/hip_cooperative_groups.h>
#include <stdint.h>

namespace cg = cooperative_groups;

typedef unsigned short u16;
typedef short s8v __attribute__((ext_vector_type(8)));   // 8 bf16 (4 VGPRs)
typedef float f4v __attribute__((ext_vector_type(4)));   // MFMA accumulator / float4

#define MFMA16(a,b,c) __builtin_amdgcn_mfma_f32_16x16x32_bf16((a),(b),(c),0,0,0)

__device__ __forceinline__ float bf2f(u16 u){ return __uint_as_float(((unsigned)u)<<16); }
__device__ __forceinline__ u16 f2bf(float f){
  unsigned u = __float_as_uint(f);
  unsigned r = u + 0x7FFFu + ((u>>16)&1u);   // RNE
  return (u16)(r>>16);
}
__device__ __forceinline__ float sigm(float x){ return 1.0f/(1.0f + __expf(-x)); }

// load 8 consecutive f32, round to bf16 fragment
__device__ __forceinline__ s8v cvt8(const float* __restrict__ p){
  f4v w0 = *(const f4v*)p;
  f4v w1 = *(const f4v*)(p + 4);
  s8v r;
  r[0]=(short)f2bf(w0[0]); r[1]=(short)f2bf(w0[1]); r[2]=(short)f2bf(w0[2]); r[3]=(short)f2bf(w0[3]);
  r[4]=(short)f2bf(w1[0]); r[5]=(short)f2bf(w1[1]); r[6]=(short)f2bf(w1[2]); r[7]=(short)f2bf(w1[3]);
  return r;
}

// ---------------- one-time: WqkT[e][h] = sum_d Wk[d][e] * Wq[d][h]  (f32 in, bf16 out) ----------------
__global__ __launch_bounds__(256) void wqk_kernel(const float* __restrict__ Wq,
                                                  const float* __restrict__ Wk,
                                                  u16* __restrict__ WqkT){
  int tid = threadIdx.x;
  int e0 = blockIdx.x * 4;
  int h0 = tid * 4;
  float acc[4][4] = {};
  for (int d = 0; d < 1024; ++d){
    float wk[4], wqv[4];
    #pragma unroll
    for (int ee = 0; ee < 4; ++ee) wk[ee] = Wk[(size_t)d*512 + e0 + ee];
    const float* wq = Wq + (size_t)d*1024 + h0;
    #pragma unroll
    for (int i = 0; i < 4; ++i) wqv[i] = wq[i];
    #pragma unroll
    for (int ee = 0; ee < 4; ++ee)
      #pragma unroll
      for (int i = 0; i < 4; ++i) acc[ee][i] += wk[ee] * wqv[i];
  }
  #pragma unroll
  for (int ee = 0; ee < 4; ++ee)
    #pragma unroll
    for (int i = 0; i < 4; ++i)
      WqkT[(size_t)(e0+ee)*1024 + h0 + i] = f2bf(acc[ee][i]);
}

// ---------------- one-time: convert LSTM weights f32 -> bf16 (same RNE as cvt8, bit-identical) -------
// wbf layout: [src(ih=0,hh=1)][4][4096][1024] bf16, linear copy of the f32 arrays.
__global__ __launch_bounds__(256) void wcvt_kernel(const float* __restrict__ w_ih,
                                                   const float* __restrict__ w_hh,
                                                   u16* __restrict__ wbf){
  const float* src = blockIdx.y ? w_hh : w_ih;
  u16* dst = wbf + (size_t)blockIdx.y * 16777216;
  size_t i = ((size_t)blockIdx.x * 256 + threadIdx.x) * 8;   // 8192 blocks * 256 thr * 8 = 16777216
  *(s8v*)(dst + i) = cvt8(src + i);
}

// ---------------- persistent decoder (BASELINE, byte-identical math): f32 weights, cvt8 per step ----
__global__ __launch_bounds__(256) void decoder_kernel(
    const int* __restrict__ tgt,
    const float* __restrict__ enc_out,   // [32][128][512] f32
    const int* __restrict__ enc_mask,
    const float* __restrict__ embedding, // [32000][512] f32
    const float* __restrict__ w_ih,      // [4][4096][1024] f32
    const float* __restrict__ w_hh,
    const float* __restrict__ b_ih,      // [4][4096] f32
    const float* __restrict__ b_hh,
    const u16* __restrict__ WqkT,        // [512][1024] bf16 (precomputed)
    u16* __restrict__ hbuf,              // [2][4][32][1024] bf16
    float* __restrict__ cbuf,            // [4][32][1024] f32
    u16* __restrict__ stepin,            // [2][32][1024] bf16
    u16* __restrict__ xcur,              // [2][32][1024] bf16
    u16* __restrict__ qbuf,              // [32][512] bf16
    u16* __restrict__ Xbuf)              // [64][32][1024] bf16
{
  cg::grid_group grid = cg::this_grid();

  __shared__ float lds[4*32*17];    // gate/qW partials, padded stride 17
  __shared__ float qlds[512];
  __shared__ float part[256];
  __shared__ float scbuf[128];
  __shared__ float red[128];
  __shared__ float wls[128];

  int tid = threadIdx.x, blk = blockIdx.x;
  int w = tid>>6, l = tid&63;
  int lm = l & 15, lk8 = (l>>4)*8;
  int j0 = blk * 4;                 // this block owns h-units j0..j0+3 (16 gate rows)

  // pre-stage: step_in[0] = [emb(tgt[:,0]), ctx=0]
  if (blk < 32){
    int b = blk, tok = tgt[b*64];
    for (int e = tid; e < 512; e += 256){
      stepin[b*1024 + e]       = f2bf(embedding[(size_t)tok*512 + e]);
      stepin[b*1024 + 512 + e] = 0;
    }
  }
  grid.sync();

  for (int t = 0; t < 64; ++t){
    const u16* si = stepin + (t&1)*32*1024;
    const u16* hr = hbuf + (t&1)*4*32*1024;
    u16*       hw = hbuf + ((t+1)&1)*4*32*1024;

    for (int L = 0; L < 4; ++L){
      const u16* xin = (L==0) ? si : (xcur + ((L-1)&1)*32*1024);
      const u16* hL  = hr + L*32*1024;
      // wave k-split: waves 0,1 -> x@w_ih, waves 2,3 -> h@w_hh, 512 K each
      const u16* A = (w < 2) ? xin : hL;
      const float* W = ((w < 2) ? w_ih : w_hh) + (size_t)L*4096*1024;
      int k0 = (w & 1)*512;
      int gg = lm >> 2, jj2 = lm & 3;   // 16 rows = 4 gates x 4 units
      const float* wrow = W + (size_t)(gg*1024 + j0 + jj2)*1024 + k0 + lk8;
      const u16* a0p  = A + lm*1024 + k0 + lk8;
      const u16* a1p  = a0p + 16*1024;
      f4v acc0 = {0.f,0.f,0.f,0.f}, acc1 = {0.f,0.f,0.f,0.f};
      #pragma unroll 4
      for (int ki = 0; ki < 16; ++ki){
        s8v bf = cvt8(wrow + ki*32);
        s8v a0 = *(const s8v*)(a0p + ki*32);
        s8v a1 = *(const s8v*)(a1p + ki*32);
        acc0 = MFMA16(a0, bf, acc0);
        acc1 = MFMA16(a1, bf, acc1);
      }
      float* slab = lds + w*32*17;
      #pragma unroll
      for (int r = 0; r < 4; ++r){
        slab[((l>>4)*4 + r)*17 + lm]        = acc0[r];
        slab[(16 + (l>>4)*4 + r)*17 + lm]   = acc1[r];
      }
      __syncthreads();
      if (tid < 128){
        int b = tid & 31, jj = tid >> 5;
        int j = j0 + jj;
        float gsum[4];
        #pragma unroll
        for (int g2 = 0; g2 < 4; ++g2){
          float s = 0.f;
          #pragma unroll
          for (int w2 = 0; w2 < 4; ++w2) s += lds[(w2*32 + b)*17 + g2*4 + jj];
          s += b_ih[L*4096 + g2*1024 + j] + b_hh[L*4096 + g2*1024 + j];
          gsum[g2] = s;
        }
        float cprev = cbuf[(L*32 + b)*1024 + j];
        float iv = sigm(gsum[0]), fv = sigm(gsum[1]);
        float gv = tanhf(gsum[2]), ov = sigm(gsum[3]);
        float cn = fv*cprev + iv*gv;
        float hn = ov*tanhf(cn);
        cbuf[(L*32 + b)*1024 + j] = cn;
        hw[(L*32 + b)*1024 + j]   = f2bf(hn);
        float xo = hn;
        if (L >= 2) xo += bf2f(si[b*1024 + j]);        // residual adds step_in
        u16 xob = f2bf(xo);
        xcur[(L&1)*32*1024 + b*1024 + j] = xob;
        if (L == 3) Xbuf[((size_t)t*32 + b)*1024 + j] = xob;
      }
      grid.sync();
    }

    // qW = x3 @ WqkT^T : blocks 0..31, 16 e-rows each, K=1024 wave-split
    if (blk < 32 && t < 63){
      int e0 = blk*16;
      const u16* xin = xcur + 1*32*1024;               // L3 wrote slot 1
      const u16* wrow = WqkT + (size_t)(e0 + lm)*1024 + w*256 + lk8;
      const u16* a0p  = xin + lm*1024 + w*256 + lk8;
      const u16* a1p  = a0p + 16*1024;
      f4v acc0 = {0.f,0.f,0.f,0.f}, acc1 = {0.f,0.f,0.f,0.f};
      #pragma unroll 4
      for (int ki = 0; ki < 8; ++ki){
        s8v bf = *(const s8v*)(wrow + ki*32);
        s8v a0 = *(const s8v*)(a0p + ki*32);
        s8v a1 = *(const s8v*)(a1p + ki*32);
        acc0 = MFMA16(a0, bf, acc0);
        acc1 = MFMA16(a1, bf, acc1);
      }
      float* slab = lds + w*32*17;
      #pragma unroll
      for (int r = 0; r < 4; ++r){
        slab[((l>>4)*4 + r)*17 + lm]      = acc0[r];
        slab[(16 + (l>>4)*4 + r)*17 + lm] = acc1[r];
      }
      __syncthreads();
      {
        int b = tid & 31, dq = tid >> 5;               // 0..7
        for (int dd = dq; dd < 16; dd += 8){
          float s = 0.f;
          #pragma unroll
          for (int w2 = 0; w2 < 4; ++w2) s += lds[(w2*32 + b)*17 + dd];
          qbuf[b*512 + e0 + dd] = f2bf(s);
        }
      }
    }
    grid.sync();

    // attention: blocks 0..31 (one per batch); scores[b,s] = qW[b,:] . enc[b,s,:]
    if (blk < 32 && t < 63){
      int b = blk;
      for (int e = tid; e < 512; e += 256) qlds[e] = bf2f(qbuf[b*512 + e]);
      __syncthreads();
      int s = tid >> 1, half = tid & 1;
      const float* ep = enc_out + ((size_t)(b*128 + s))*512 + half*256;
      float acc = 0.f;
      #pragma unroll 4
      for (int k = 0; k < 64; ++k){
        f4v v = *(const f4v*)(ep + k*4);
        #pragma unroll
        for (int j = 0; j < 4; ++j) acc += qlds[half*256 + k*4 + j] * v[j];
      }
      part[tid] = acc;
      __syncthreads();
      if (tid < 128){
        float sc = (part[tid*2] + part[tid*2+1]) * 0.03125f;   // 1/sqrt(1024)
        if (enc_mask[b*128 + tid] == 0) sc = -10000.0f;
        scbuf[tid] = sc; red[tid] = sc;
      }
      __syncthreads();
      for (int off = 64; off >= 1; off >>= 1){
        if (tid < off) red[tid] = fmaxf(red[tid], red[tid+off]);
        __syncthreads();
      }
      float mx = red[0];
      __syncthreads();
      if (tid < 128){ float e = __expf(scbuf[tid] - mx); wls[tid] = e; red[tid] = e; }
      __syncthreads();
      for (int off = 64; off >= 1; off >>= 1){
        if (tid < off) red[tid] += red[tid+off];
        __syncthreads();
      }
      float inv = 1.0f / red[0];
      float a0 = 0.f, a1 = 0.f;
      const float* eb = enc_out + (size_t)b*128*512;
      for (int s2 = 0; s2 < 128; ++s2){
        float wv = wls[s2];
        a0 += wv * eb[s2*512 + tid];
        a1 += wv * eb[s2*512 + 256 + tid];
      }
      {
        u16* so = stepin + ((t+1)&1)*32*1024 + b*1024;
        so[512 + tid]       = f2bf(a0*inv);
        so[512 + 256 + tid] = f2bf(a1*inv);
        int tok = tgt[b*64 + t + 1];
        so[tid]       = f2bf(embedding[(size_t)tok*512 + tid]);
        so[256 + tid] = f2bf(embedding[(size_t)tok*512 + 256 + tid]);
      }
    }
    grid.sync();
  }
}

// ---------------- decoder variant: identical except weights read from precomputed bf16 --------------
__global__ __launch_bounds__(256) void decoder_kernel_bf(
    const int* __restrict__ tgt,
    const float* __restrict__ enc_out,
    const int* __restrict__ enc_mask,
    const float* __restrict__ embedding,
    const u16* __restrict__ wbf,         // [2][4][4096][1024] bf16 (0=ih, 1=hh)
    const float* __restrict__ b_ih,
    const float* __restrict__ b_hh,
    const u16* __restrict__ WqkT,
    u16* __restrict__ hbuf,
    float* __restrict__ cbuf,
    u16* __restrict__ stepin,
    u16* __restrict__ xcur,
    u16* __restrict__ qbuf,
    u16* __restrict__ Xbuf)
{
  cg::grid_group grid = cg::this_grid();

  __shared__ float lds[4*32*17];
  __shared__ float qlds[512];
  __shared__ float part[256];
  __shared__ float scbuf[128];
  __shared__ float red[128];
  __shared__ float wls[128];

  int tid = threadIdx.x, blk = blockIdx.x;
  int w = tid>>6, l = tid&63;
  int lm = l & 15, lk8 = (l>>4)*8;
  int j0 = blk * 4;

  if (blk < 32){
    int b = blk, tok = tgt[b*64];
    for (int e = tid; e < 512; e += 256){
      stepin[b*1024 + e]       = f2bf(embedding[(size_t)tok*512 + e]);
      stepin[b*1024 + 512 + e] = 0;
    }
  }
  grid.sync();

  for (int t = 0; t < 64; ++t){
    const u16* si = stepin + (t&1)*32*1024;
    const u16* hr = hbuf + (t&1)*4*32*1024;
    u16*       hw = hbuf + ((t+1)&1)*4*32*1024;

    for (int L = 0; L < 4; ++L){
      const u16* xin = (L==0) ? si : (xcur + ((L-1)&1)*32*1024);
      const u16* hL  = hr + L*32*1024;
      const u16* A = (w < 2) ? xin : hL;
      // ONLY change vs baseline: W fragments come pre-rounded from wbf (bit-identical values)
      const u16* Wb = wbf + ((w < 2) ? (size_t)0 : (size_t)16777216) + (size_t)L*4096*1024;
      int k0 = (w & 1)*512;
      int gg = lm >> 2, jj2 = lm & 3;
      const u16* wrow = Wb + (size_t)(gg*1024 + j0 + jj2)*1024 + k0 + lk8;
      const u16* a0p  = A + lm*1024 + k0 + lk8;
      const u16* a1p  = a0p + 16*1024;
      f4v acc0 = {0.f,0.f,0.f,0.f}, acc1 = {0.f,0.f,0.f,0.f};
      #pragma unroll 4
      for (int ki = 0; ki < 16; ++ki){
        s8v bf = *(const s8v*)(wrow + ki*32);
        s8v a0 = *(const s8v*)(a0p + ki*32);
        s8v a1 = *(const s8v*)(a1p + ki*32);
        acc0 = MFMA16(a0, bf, acc0);
        acc1 = MFMA16(a1, bf, acc1);
      }
      float* slab = lds + w*32*17;
      #pragma unroll
      for (int r = 0; r < 4; ++r){
        slab[((l>>4)*4 + r)*17 + lm]        = acc0[r];
        slab[(16 + (l>>4)*4 + r)*17 + lm]   = acc1[r];
      }
      __syncthreads();
      if (tid < 128){
        int b = tid & 31, jj = tid >> 5;
        int j = j0 + jj;
        float gsum[4];
        #pragma unroll
        for (int g2 = 0; g2 < 4; ++g2){
          float s = 0.f;
          #pragma unroll
          for (int w2 = 0; w2 < 4; ++w2) s += lds[(w2*32 + b)*17 + g2*4 + jj];
          s += b_ih[L*4096 + g2*1024 + j] + b_hh[L*4096 + g2*1024 + j];
          gsum[g2] = s;
        }
        float cprev = cbuf[(L*32 + b)*1024 + j];
        float iv = sigm(gsum[0]), fv = sigm(gsum[1]);
        float gv = tanhf(gsum[2]), ov = sigm(gsum[3]);
        float cn = fv*cprev + iv*gv;
        float hn = ov*tanhf(cn);
        cbuf[(L*32 + b)*1024 + j] = cn;
        hw[(L*32 + b)*1024 + j]   = f2bf(hn);
        float xo = hn;
        if (L >= 2) xo += bf2f(si[b*1024 + j]);
        u16 xob = f2bf(xo);
        xcur[(L&1)*32*1024 + b*1024 + j] = xob;
        if (L == 3) Xbuf[((size_t)t*32 + b)*1024 + j] = xob;
      }
      grid.sync();
    }

    if (blk < 32 && t < 63){
      int e0 = blk*16;
      const u16* xin = xcur + 1*32*1024;
      const u16* wrow = WqkT + (size_t)(e0 + lm)*1024 + w*256 + lk8;
      const u16* a0p  = xin + lm*1024 + w*256 + lk8;
      const u16* a1p  = a0p + 16*1024;
      f4v acc0 = {0.f,0.f,0.f,0.f}, acc1 = {0.f,0.f,0.f,0.f};
      #pragma unroll 4
      for (int ki = 0; ki < 8; ++ki){
        s8v bf = *(const s8v*)(wrow + ki*32);
        s8v a0 = *(const s8v*)(a0p + ki*32);
        s8v a1 = *(const s8v*)(a1p + ki*32);
        acc0 = MFMA16(a0, bf, acc0);
        acc1 = MFMA16(a1, bf, acc1);
      }
      float* slab = lds + w*32*17;
      #pragma unroll
      for (int r = 0; r < 4; ++r){
        slab[((l>>4)*4 + r)*17 + lm]      = acc0[r];
        slab[(16 + (l>>4)*4 + r)*17 + lm] = acc1[r];
      }
      __syncthreads();
      {
        int b = tid & 31, dq = tid >> 5;
        for (int dd = dq; dd < 16; dd += 8){
          float s = 0.f;
          #pragma unroll
          for (int w2 = 0; w2 < 4; ++w2) s += lds[(w2*32 + b)*17 + dd];
          qbuf[b*512 + e0 + dd] = f2bf(s);
        }
      }
    }
    grid.sync();

    if (blk < 32 && t < 63){
      int b = blk;
      for (int e = tid; e < 512; e += 256) qlds[e] = bf2f(qbuf[b*512 + e]);
      __syncthreads();
      int s = tid >> 1, half = tid & 1;
      const float* ep = enc_out + ((size_t)(b*128 + s))*512 + half*256;
      float acc = 0.f;
      #pragma unroll 4
      for (int k = 0; k < 64; ++k){
        f4v v = *(const f4v*)(ep + k*4);
        #pragma unroll
        for (int j = 0; j < 4; ++j) acc += qlds[half*256 + k*4 + j] * v[j];
      }
      part[tid] = acc;
      __syncthreads();
      if (tid < 128){
        float sc = (part[tid*2] + part[tid*2+1]) * 0.03125f;
        if (enc_mask[b*128 + tid] == 0) sc = -10000.0f;
        scbuf[tid] = sc; red[tid] = sc;
      }
      __syncthreads();
      for (int off = 64; off >= 1; off >>= 1){
        if (tid < off) red[tid] = fmaxf(red[tid], red[tid+off]);
        __syncthreads();
      }
      float mx = red[0];
      __syncthreads();
      if (tid < 128){ float e = __expf(scbuf[tid] - mx); wls[tid] = e; red[tid] = e; }
      __syncthreads();
      for (int off = 64; off >= 1; off >>= 1){
        if (tid < off) red[tid] += red[tid+off];
        __syncthreads();
      }
      float inv = 1.0f / red[0];
      float a0 = 0.f, a1 = 0.f;
      const float* eb = enc_out + (size_t)b*128*512;
      for (int s2 = 0; s2 < 128; ++s2){
        float wv = wls[s2];
        a0 += wv * eb[s2*512 + tid];
        a1 += wv * eb[s2*512 + 256 + tid];
      }
      {
        u16* so = stepin + ((t+1)&1)*32*1024 + b*1024;
        so[512 + tid]       = f2bf(a0*inv);
        so[512 + 256 + tid] = f2bf(a1*inv);
        int tok = tgt[b*64 + t + 1];
        so[tid]       = f2bf(embedding[(size_t)tok*512 + tid]);
        so[256 + tid] = f2bf(embedding[(size_t)tok*512 + 256 + tid]);
      }
    }
    grid.sync();
  }
}

// ---------------- projection: out[b][t][v] = X[t][b] @ proj_w.T + proj_b ----------------
// 128x128 tile, BK=64, MFMA 16x16x32; pw is f32, converted to bf16 during LDS staging.
__global__ __launch_bounds__(256) void proj_kernel(const u16* __restrict__ X,
                                                   const float* __restrict__ pw,
                                                   const float* __restrict__ pb,
                                                   float* __restrict__ out){
  __shared__ u16 As[128*64];
  __shared__ u16 Bs[128*64];
  int tid = threadIdx.x;
  int n0 = blockIdx.x*128, m0 = blockIdx.y*128;
  int w = tid>>6, l = tid&63;
  int wm = w & 1, wn = w >> 1;
  int lm = l & 15, lk8 = (l>>4)*8;
  f4v acc[4][4] = {};
  for (int kb = 0; kb < 16; ++kb){
    int k0 = kb*64;
    #pragma unroll
    for (int i = 0; i < 4; ++i){
      int c = tid*4 + i, row = c>>3, koff = (c&7)*8;
      *(s8v*)&As[row*64 + koff] = *(const s8v*)&X[(size_t)(m0+row)*1024 + k0 + koff];
      *(s8v*)&Bs[row*64 + koff] = cvt8(&pw[(size_t)(n0+row)*1024 + k0 + koff]);
    }
    __syncthreads();
    #pragma unroll
    for (int ki = 0; ki < 2; ++ki){
      s8v av[4], bv[4];
      #pragma unroll
      for (int mt = 0; mt < 4; ++mt) av[mt] = *(const s8v*)&As[(wm*64 + mt*16 + lm)*64 + ki*32 + lk8];
      #pragma unroll
      for (int nt = 0; nt < 4; ++nt) bv[nt] = *(const s8v*)&Bs[(wn*64 + nt*16 + lm)*64 + ki*32 + lk8];
      #pragma unroll
      for (int mt = 0; mt < 4; ++mt)
        #pragma unroll
        for (int nt = 0; nt < 4; ++nt)
          acc[mt][nt] = MFMA16(av[mt], bv[nt], acc[mt][nt]);
    }
    __syncthreads();
  }
  #pragma unroll
  for (int mt = 0; mt < 4; ++mt){
    #pragma unroll
    for (int r = 0; r < 4; ++r){
      int m = m0 + wm*64 + mt*16 + (l>>4)*4 + r;
      int tt = m >> 5, b = m & 31;                    // m = t*32 + b
      size_t obase = ((size_t)(b*64 + tt))*32000;
      #pragma unroll
      for (int nt = 0; nt < 4; ++nt){
        int nn = n0 + wn*64 + nt*16 + lm;
        out[obase + nn] = acc[mt][nt][r] + pb[nn];
      }
    }
  }
}

extern "C" void kernel_launch(void* const* d_in, const int* in_sizes, int n_in,
                              void* d_out, int out_size, void* d_ws, size_t ws_size,
                              hipStream_t stream){
  (void)in_sizes; (void)n_in; (void)out_size;
  const int*   tgt       = (const int*)d_in[0];
  const float* enc_out   = (const float*)d_in[2];
  const int*   enc_mask  = (const int*)d_in[3];
  const float* embedding = (const float*)d_in[4];
  const float* w_ih      = (const float*)d_in[5];
  const float* w_hh      = (const float*)d_in[6];
  const float* b_ih      = (const float*)d_in[7];
  const float* b_hh      = (const float*)d_in[8];
  const float* Wq        = (const float*)d_in[9];
  const float* Wk        = (const float*)d_in[10];
  const float* proj_w    = (const float*)d_in[11];
  const float* proj_b    = (const float*)d_in[12];

  // compact workspace: 6.6 MB known-good core + optional 64 MB bf16 weight mirror
  char* ws = (char*)d_ws;
  u16*  hbuf   = (u16*)  (ws + 0);                      // 524288 B
  float* cbuf  = (float*)(ws + 524288);                 // 524288 B  (zeroed region ends 1048576)
  u16*  stepin = (u16*)  (ws + 1048576);                // 131072 B
  u16*  xcur   = (u16*)  (ws + 1179648);                // 131072 B
  u16*  qbuf   = (u16*)  (ws + 1310720);                // 32768 B
  u16*  WqkT   = (u16*)  (ws + 1343488);                // 1048576 B
  u16*  Xbuf   = (u16*)  (ws + 2392064);                // 4194304 B -> core total 6586368 B
  u16*  wbf    = (u16*)  (ws + 6586368);                // optional 67108864 B (2 x [4][4096][1024] bf16)

  const size_t WS_CORE = 6586368;
  const size_t WBF_BYTES = 2ull * 16777216ull * 2ull;   // 67108864
  int use_bf = (ws_size >= WS_CORE + WBF_BYTES) ? 1 : 0;

  hipMemsetAsync(d_ws, 0, 1048576, stream);             // h0 + c0 = zeros
  wqk_kernel<<<128, 256, 0, stream>>>(Wq, Wk, WqkT);

  if (use_bf){
    wcvt_kernel<<<dim3(8192, 2), 256, 0, stream>>>(w_ih, w_hh, wbf);
    void* args[] = { (void*)&tgt, (void*)&enc_out, (void*)&enc_mask, (void*)&embedding,
                     (void*)&wbf, (void*)&b_ih, (void*)&b_hh, (void*)&WqkT,
                     (void*)&hbuf, (void*)&cbuf, (void*)&stepin, (void*)&xcur,
                     (void*)&qbuf, (void*)&Xbuf };
    hipLaunchCooperativeKernel((void*)decoder_kernel_bf, dim3(256), dim3(256), args, 0, stream);
  } else {
    void* args[] = { (void*)&tgt, (void*)&enc_out, (void*)&enc_mask, (void*)&embedding,
                     (void*)&w_ih, (void*)&w_hh, (void*)&b_ih, (void*)&b_hh, (void*)&WqkT,
                     (void*)&hbuf, (void*)&cbuf, (void*)&stepin, (void*)&xcur,
                     (void*)&qbuf, (void*)&Xbuf };
    hipLaunchCooperativeKernel((void*)decoder_kernel, dim3(256), dim3(256), args, 0, stream);
  }

  dim3 pgrid(250, 16);
  proj_kernel<<<pgrid, 256, 0, stream>>>(Xbuf, proj_w, proj_b, (float*)d_out);
}

// Round 4
// 6001.011 us; speedup vs baseline: 2.7173x; 2.5377x over previous
//
#include <hip/hip_runtime.h>
#include <hip/hip_cooperative_groups.h>
#include <stdint.h>

namespace cg = cooperative_groups;

typedef unsigned short u16;
typedef short s8v __attribute__((ext_vector_type(8)));   // 8 bf16 (4 VGPRs)
typedef float f4v __attribute__((ext_vector_type(4)));   // MFMA accumulator / float4

#define MFMA16(a,b,c) __builtin_amdgcn_mfma_f32_16x16x32_bf16((a),(b),(c),0,0,0)

__device__ __forceinline__ float bf2f(u16 u){ return __uint_as_float(((unsigned)u)<<16); }
__device__ __forceinline__ u16 f2bf(float f){
  unsigned u = __float_as_uint(f);
  unsigned r = u + 0x7FFFu + ((u>>16)&1u);   // RNE
  return (u16)(r>>16);
}
__device__ __forceinline__ float sigm(float x){ return 1.0f/(1.0f + __expf(-x)); }

// load 8 consecutive f32, round to bf16 fragment
__device__ __forceinline__ s8v cvt8(const float* __restrict__ p){
  f4v w0 = *(const f4v*)p;
  f4v w1 = *(const f4v*)(p + 4);
  s8v r;
  r[0]=(short)f2bf(w0[0]); r[1]=(short)f2bf(w0[1]); r[2]=(short)f2bf(w0[2]); r[3]=(short)f2bf(w0[3]);
  r[4]=(short)f2bf(w1[0]); r[5]=(short)f2bf(w1[1]); r[6]=(short)f2bf(w1[2]); r[7]=(short)f2bf(w1[3]);
  return r;
}

// ---- device-coherent (cross-XCD) access helpers: data goes through L3, never dirty in an L2 ----
__device__ __forceinline__ s8v cload8(const u16* p){           // 16B coherent load (2x b64 atomic)
  union { unsigned long long q[2]; s8v v; } u;
  u.q[0] = __hip_atomic_load((const unsigned long long*)p,     __ATOMIC_RELAXED, __HIP_MEMORY_SCOPE_AGENT);
  u.q[1] = __hip_atomic_load((const unsigned long long*)p + 1, __ATOMIC_RELAXED, __HIP_MEMORY_SCOPE_AGENT);
  return u.v;
}
__device__ __forceinline__ unsigned cld32(const u16* p){       // aligned dword coherent load
  return __hip_atomic_load((const unsigned*)p, __ATOMIC_RELAXED, __HIP_MEMORY_SCOPE_AGENT);
}
__device__ __forceinline__ void cst16(u16* p, u16 v){          // u16 coherent store (write-through)
  asm volatile("global_store_short %0, %1, off sc0 sc1" :: "v"(p), "v"((unsigned)v) : "memory");
}

// ---- lightweight grid barrier: relaxed agent atomics only (no L2 writeback/invalidate) ----
// Release safety: __syncthreads() drains each wave's vmcnt (sc1 stores ack at L3) before the
// arrival atomic; readers re-fetch from L3 via coherent loads after the barrier.
__device__ __forceinline__ void gbar(unsigned* cnt, unsigned* gen, int tid){
  __syncthreads();
  if (tid == 0){
    unsigned old = __hip_atomic_fetch_add(cnt, 1u, __ATOMIC_RELAXED, __HIP_MEMORY_SCOPE_AGENT);
    unsigned r = old >> 8;                       // NBLK = 256
    if ((old & 255u) == 255u){
      __hip_atomic_store(gen, r + 1u, __ATOMIC_RELAXED, __HIP_MEMORY_SCOPE_AGENT);
    } else {
      while (__hip_atomic_load(gen, __ATOMIC_RELAXED, __HIP_MEMORY_SCOPE_AGENT) < r + 1u)
        __builtin_amdgcn_s_sleep(4);
    }
  }
  __syncthreads();
}

// ---------------- one-time: WqkT[e][h] = sum_d Wk[d][e] * Wq[d][h]  (f32 in, bf16 out) ----------------
__global__ __launch_bounds__(256) void wqk_kernel(const float* __restrict__ Wq,
                                                  const float* __restrict__ Wk,
                                                  u16* __restrict__ WqkT){
  int tid = threadIdx.x;
  int e0 = blockIdx.x * 4;
  int h0 = tid * 4;
  float acc[4][4] = {};
  for (int d = 0; d < 1024; ++d){
    float wk[4], wqv[4];
    #pragma unroll
    for (int ee = 0; ee < 4; ++ee) wk[ee] = Wk[(size_t)d*512 + e0 + ee];
    const float* wq = Wq + (size_t)d*1024 + h0;
    #pragma unroll
    for (int i = 0; i < 4; ++i) wqv[i] = wq[i];
    #pragma unroll
    for (int ee = 0; ee < 4; ++ee)
      #pragma unroll
      for (int i = 0; i < 4; ++i) acc[ee][i] += wk[ee] * wqv[i];
  }
  #pragma unroll
  for (int ee = 0; ee < 4; ++ee)
    #pragma unroll
    for (int i = 0; i < 4; ++i)
      WqkT[(size_t)(e0+ee)*1024 + h0 + i] = f2bf(acc[ee][i]);
}

// ---------------- one-time: convert LSTM weights f32 -> bf16 (same RNE as cvt8, bit-identical) -------
__global__ __launch_bounds__(256) void wcvt_kernel(const float* __restrict__ w_ih,
                                                   const float* __restrict__ w_hh,
                                                   u16* __restrict__ wbf){
  const float* src = blockIdx.y ? w_hh : w_ih;
  u16* dst = wbf + (size_t)blockIdx.y * 16777216;
  size_t i = ((size_t)blockIdx.x * 256 + threadIdx.x) * 8;   // 8192 blocks * 256 thr * 8 = 16777216
  *(s8v*)(dst + i) = cvt8(src + i);
}

// ---------------- FAST decoder: bf16 weights + custom barrier + coherent shared buffers -------------
__global__ __launch_bounds__(256) void decoder_kernel_bf2(
    const int* __restrict__ tgt,
    const float* __restrict__ enc_out,   // [32][128][512] f32 (read-only)
    const int* __restrict__ enc_mask,
    const float* __restrict__ embedding, // [32000][512] f32 (read-only)
    const u16* __restrict__ wbf,         // [2][4][4096][1024] bf16 (read-only)
    const float* __restrict__ b_ih,
    const float* __restrict__ b_hh,
    const u16* __restrict__ WqkT,        // read-only
    u16* __restrict__ hbuf,              // shared rw -> coherent
    float* __restrict__ cbuf,            // block-private -> normal
    u16* __restrict__ stepin,            // shared rw -> coherent
    u16* __restrict__ xcur,              // shared rw -> coherent
    u16* __restrict__ qbuf,              // shared rw -> coherent
    u16* __restrict__ Xbuf,              // written here, read by next kernel -> normal
    unsigned* __restrict__ barcnt,
    unsigned* __restrict__ bargen)
{
  __shared__ float lds[4*32*17];
  __shared__ float qlds[512];
  __shared__ float part[256];
  __shared__ float scbuf[128];
  __shared__ float red[128];
  __shared__ float wls[128];

  int tid = threadIdx.x, blk = blockIdx.x;
  int w = tid>>6, l = tid&63;
  int lm = l & 15, lk8 = (l>>4)*8;
  int j0 = blk * 4;                 // this block owns h-units j0..j0+3 (16 gate rows)

  // pre-stage: step_in[0] = [emb(tgt[:,0]), ctx=0]
  if (blk < 32){
    int b = blk, tok = tgt[b*64];
    for (int e = tid; e < 512; e += 256){
      cst16(stepin + b*1024 + e,       f2bf(embedding[(size_t)tok*512 + e]));
      cst16(stepin + b*1024 + 512 + e, (u16)0);
    }
  }
  gbar(barcnt, bargen, tid);

  for (int t = 0; t < 64; ++t){
    const u16* si = stepin + (t&1)*32*1024;
    const u16* hr = hbuf + (t&1)*4*32*1024;
    u16*       hw = hbuf + ((t+1)&1)*4*32*1024;

    for (int L = 0; L < 4; ++L){
      const u16* xin = (L==0) ? si : (xcur + ((L-1)&1)*32*1024);
      const u16* hL  = hr + L*32*1024;
      const u16* A = (w < 2) ? xin : hL;
      const u16* Wb = wbf + ((w < 2) ? (size_t)0 : (size_t)16777216) + (size_t)L*4096*1024;
      int k0 = (w & 1)*512;
      int gg = lm >> 2, jj2 = lm & 3;   // 16 rows = 4 gates x 4 units
      const u16* wrow = Wb + (size_t)(gg*1024 + j0 + jj2)*1024 + k0 + lk8;
      const u16* a0p  = A + lm*1024 + k0 + lk8;
      const u16* a1p  = a0p + 16*1024;
      f4v acc0 = {0.f,0.f,0.f,0.f}, acc1 = {0.f,0.f,0.f,0.f};
      #pragma unroll 4
      for (int ki = 0; ki < 16; ++ki){
        s8v bf = *(const s8v*)(wrow + ki*32);    // weights: normal cached load
        s8v a0 = cload8(a0p + ki*32);            // activations: coherent
        s8v a1 = cload8(a1p + ki*32);
        acc0 = MFMA16(a0, bf, acc0);
        acc1 = MFMA16(a1, bf, acc1);
      }
      float* slab = lds + w*32*17;
      #pragma unroll
      for (int r = 0; r < 4; ++r){
        slab[((l>>4)*4 + r)*17 + lm]        = acc0[r];
        slab[(16 + (l>>4)*4 + r)*17 + lm]   = acc1[r];
      }
      __syncthreads();
      if (tid < 128){
        int b = tid & 31, jj = tid >> 5;
        int j = j0 + jj;
        float gsum[4];
        #pragma unroll
        for (int g2 = 0; g2 < 4; ++g2){
          float s = 0.f;
          #pragma unroll
          for (int w2 = 0; w2 < 4; ++w2) s += lds[(w2*32 + b)*17 + g2*4 + jj];
          s += b_ih[L*4096 + g2*1024 + j] + b_hh[L*4096 + g2*1024 + j];
          gsum[g2] = s;
        }
        float cprev = cbuf[(L*32 + b)*1024 + j];
        float iv = sigm(gsum[0]), fv = sigm(gsum[1]);
        float gv = tanhf(gsum[2]), ov = sigm(gsum[3]);
        float cn = fv*cprev + iv*gv;
        float hn = ov*tanhf(cn);
        cbuf[(L*32 + b)*1024 + j] = cn;          // block-private: normal
        cst16(hw + (L*32 + b)*1024 + j, f2bf(hn));
        float xo = hn;
        if (L >= 2){                              // residual adds step_in (coherent dword read)
          unsigned sidx = (unsigned)(b*1024 + j);
          unsigned dw = cld32(si + (sidx & ~1u));
          xo += bf2f((u16)((sidx & 1u) ? (dw >> 16) : (dw & 0xffffu)));
        }
        u16 xob = f2bf(xo);
        cst16(xcur + (L&1)*32*1024 + b*1024 + j, xob);
        if (L == 3) Xbuf[((size_t)t*32 + b)*1024 + j] = xob;   // consumed by proj kernel
      }
      gbar(barcnt, bargen, tid);
    }

    // qW = x3 @ WqkT^T : blocks 0..31, 16 e-rows each, K=1024 wave-split
    if (blk < 32 && t < 63){
      int e0 = blk*16;
      const u16* xin = xcur + 1*32*1024;               // L3 wrote slot 1
      const u16* wrow = WqkT + (size_t)(e0 + lm)*1024 + w*256 + lk8;
      const u16* a0p  = xin + lm*1024 + w*256 + lk8;
      const u16* a1p  = a0p + 16*1024;
      f4v acc0 = {0.f,0.f,0.f,0.f}, acc1 = {0.f,0.f,0.f,0.f};
      #pragma unroll 4
      for (int ki = 0; ki < 8; ++ki){
        s8v bf = *(const s8v*)(wrow + ki*32);
        s8v a0 = cload8(a0p + ki*32);
        s8v a1 = cload8(a1p + ki*32);
        acc0 = MFMA16(a0, bf, acc0);
        acc1 = MFMA16(a1, bf, acc1);
      }
      float* slab = lds + w*32*17;
      #pragma unroll
      for (int r = 0; r < 4; ++r){
        slab[((l>>4)*4 + r)*17 + lm]      = acc0[r];
        slab[(16 + (l>>4)*4 + r)*17 + lm] = acc1[r];
      }
      __syncthreads();
      {
        int b = tid & 31, dq = tid >> 5;               // 0..7
        for (int dd = dq; dd < 16; dd += 8){
          float s = 0.f;
          #pragma unroll
          for (int w2 = 0; w2 < 4; ++w2) s += lds[(w2*32 + b)*17 + dd];
          cst16(qbuf + b*512 + e0 + dd, f2bf(s));
        }
      }
    }
    gbar(barcnt, bargen, tid);

    // attention: blocks 0..31 (one per batch); scores[b,s] = qW[b,:] . enc[b,s,:]
    if (blk < 32 && t < 63){
      int b = blk;
      {
        unsigned d = cld32(qbuf + b*512 + 2*tid);      // 256 dwords = 512 u16, coherent
        qlds[2*tid]     = bf2f((u16)(d & 0xffffu));
        qlds[2*tid + 1] = bf2f((u16)(d >> 16));
      }
      __syncthreads();
      int s = tid >> 1, half = tid & 1;
      const float* ep = enc_out + ((size_t)(b*128 + s))*512 + half*256;
      float acc = 0.f;
      #pragma unroll 4
      for (int k = 0; k < 64; ++k){
        f4v v = *(const f4v*)(ep + k*4);
        #pragma unroll
        for (int j = 0; j < 4; ++j) acc += qlds[half*256 + k*4 + j] * v[j];
      }
      part[tid] = acc;
      __syncthreads();
      if (tid < 128){
        float sc = (part[tid*2] + part[tid*2+1]) * 0.03125f;   // 1/sqrt(1024)
        if (enc_mask[b*128 + tid] == 0) sc = -10000.0f;
        scbuf[tid] = sc; red[tid] = sc;
      }
      __syncthreads();
      for (int off = 64; off >= 1; off >>= 1){
        if (tid < off) red[tid] = fmaxf(red[tid], red[tid+off]);
        __syncthreads();
      }
      float mx = red[0];
      __syncthreads();
      if (tid < 128){ float e = __expf(scbuf[tid] - mx); wls[tid] = e; red[tid] = e; }
      __syncthreads();
      for (int off = 64; off >= 1; off >>= 1){
        if (tid < off) red[tid] += red[tid+off];
        __syncthreads();
      }
      float inv = 1.0f / red[0];
      float a0 = 0.f, a1 = 0.f;
      const float* eb = enc_out + (size_t)b*128*512;
      for (int s2 = 0; s2 < 128; ++s2){
        float wv = wls[s2];
        a0 += wv * eb[s2*512 + tid];
        a1 += wv * eb[s2*512 + 256 + tid];
      }
      {
        u16* so = stepin + ((t+1)&1)*32*1024 + b*1024;
        cst16(so + 512 + tid,       f2bf(a0*inv));
        cst16(so + 512 + 256 + tid, f2bf(a1*inv));
        int tok = tgt[b*64 + t + 1];
        cst16(so + tid,       f2bf(embedding[(size_t)tok*512 + tid]));
        cst16(so + 256 + tid, f2bf(embedding[(size_t)tok*512 + 256 + tid]));
      }
    }
    gbar(barcnt, bargen, tid);
  }
}

// ---------------- FALLBACK decoder (round-3, cg grid.sync, bf16 weights) ----------------------------
__global__ __launch_bounds__(256) void decoder_kernel_bf(
    const int* __restrict__ tgt,
    const float* __restrict__ enc_out,
    const int* __restrict__ enc_mask,
    const float* __restrict__ embedding,
    const u16* __restrict__ wbf,
    const float* __restrict__ b_ih,
    const float* __restrict__ b_hh,
    const u16* __restrict__ WqkT,
    u16* __restrict__ hbuf,
    float* __restrict__ cbuf,
    u16* __restrict__ stepin,
    u16* __restrict__ xcur,
    u16* __restrict__ qbuf,
    u16* __restrict__ Xbuf)
{
  cg::grid_group grid = cg::this_grid();

  __shared__ float lds[4*32*17];
  __shared__ float qlds[512];
  __shared__ float part[256];
  __shared__ float scbuf[128];
  __shared__ float red[128];
  __shared__ float wls[128];

  int tid = threadIdx.x, blk = blockIdx.x;
  int w = tid>>6, l = tid&63;
  int lm = l & 15, lk8 = (l>>4)*8;
  int j0 = blk * 4;

  if (blk < 32){
    int b = blk, tok = tgt[b*64];
    for (int e = tid; e < 512; e += 256){
      stepin[b*1024 + e]       = f2bf(embedding[(size_t)tok*512 + e]);
      stepin[b*1024 + 512 + e] = 0;
    }
  }
  grid.sync();

  for (int t = 0; t < 64; ++t){
    const u16* si = stepin + (t&1)*32*1024;
    const u16* hr = hbuf + (t&1)*4*32*1024;
    u16*       hw = hbuf + ((t+1)&1)*4*32*1024;

    for (int L = 0; L < 4; ++L){
      const u16* xin = (L==0) ? si : (xcur + ((L-1)&1)*32*1024);
      const u16* hL  = hr + L*32*1024;
      const u16* A = (w < 2) ? xin : hL;
      const u16* Wb = wbf + ((w < 2) ? (size_t)0 : (size_t)16777216) + (size_t)L*4096*1024;
      int k0 = (w & 1)*512;
      int gg = lm >> 2, jj2 = lm & 3;
      const u16* wrow = Wb + (size_t)(gg*1024 + j0 + jj2)*1024 + k0 + lk8;
      const u16* a0p  = A + lm*1024 + k0 + lk8;
      const u16* a1p  = a0p + 16*1024;
      f4v acc0 = {0.f,0.f,0.f,0.f}, acc1 = {0.f,0.f,0.f,0.f};
      #pragma unroll 4
      for (int ki = 0; ki < 16; ++ki){
        s8v bf = *(const s8v*)(wrow + ki*32);
        s8v a0 = *(const s8v*)(a0p + ki*32);
        s8v a1 = *(const s8v*)(a1p + ki*32);
        acc0 = MFMA16(a0, bf, acc0);
        acc1 = MFMA16(a1, bf, acc1);
      }
      float* slab = lds + w*32*17;
      #pragma unroll
      for (int r = 0; r < 4; ++r){
        slab[((l>>4)*4 + r)*17 + lm]        = acc0[r];
        slab[(16 + (l>>4)*4 + r)*17 + lm]   = acc1[r];
      }
      __syncthreads();
      if (tid < 128){
        int b = tid & 31, jj = tid >> 5;
        int j = j0 + jj;
        float gsum[4];
        #pragma unroll
        for (int g2 = 0; g2 < 4; ++g2){
          float s = 0.f;
          #pragma unroll
          for (int w2 = 0; w2 < 4; ++w2) s += lds[(w2*32 + b)*17 + g2*4 + jj];
          s += b_ih[L*4096 + g2*1024 + j] + b_hh[L*4096 + g2*1024 + j];
          gsum[g2] = s;
        }
        float cprev = cbuf[(L*32 + b)*1024 + j];
        float iv = sigm(gsum[0]), fv = sigm(gsum[1]);
        float gv = tanhf(gsum[2]), ov = sigm(gsum[3]);
        float cn = fv*cprev + iv*gv;
        float hn = ov*tanhf(cn);
        cbuf[(L*32 + b)*1024 + j] = cn;
        hw[(L*32 + b)*1024 + j]   = f2bf(hn);
        float xo = hn;
        if (L >= 2) xo += bf2f(si[b*1024 + j]);
        u16 xob = f2bf(xo);
        xcur[(L&1)*32*1024 + b*1024 + j] = xob;
        if (L == 3) Xbuf[((size_t)t*32 + b)*1024 + j] = xob;
      }
      grid.sync();
    }

    if (blk < 32 && t < 63){
      int e0 = blk*16;
      const u16* xin = xcur + 1*32*1024;
      const u16* wrow = WqkT + (size_t)(e0 + lm)*1024 + w*256 + lk8;
      const u16* a0p  = xin + lm*1024 + w*256 + lk8;
      const u16* a1p  = a0p + 16*1024;
      f4v acc0 = {0.f,0.f,0.f,0.f}, acc1 = {0.f,0.f,0.f,0.f};
      #pragma unroll 4
      for (int ki = 0; ki < 8; ++ki){
        s8v bf = *(const s8v*)(wrow + ki*32);
        s8v a0 = *(const s8v*)(a0p + ki*32);
        s8v a1 = *(const s8v*)(a1p + ki*32);
        acc0 = MFMA16(a0, bf, acc0);
        acc1 = MFMA16(a1, bf, acc1);
      }
      float* slab = lds + w*32*17;
      #pragma unroll
      for (int r = 0; r < 4; ++r){
        slab[((l>>4)*4 + r)*17 + lm]      = acc0[r];
        slab[(16 + (l>>4)*4 + r)*17 + lm] = acc1[r];
      }
      __syncthreads();
      {
        int b = tid & 31, dq = tid >> 5;
        for (int dd = dq; dd < 16; dd += 8){
          float s = 0.f;
          #pragma unroll
          for (int w2 = 0; w2 < 4; ++w2) s += lds[(w2*32 + b)*17 + dd];
          qbuf[b*512 + e0 + dd] = f2bf(s);
        }
      }
    }
    grid.sync();

    if (blk < 32 && t < 63){
      int b = blk;
      for (int e = tid; e < 512; e += 256) qlds[e] = bf2f(qbuf[b*512 + e]);
      __syncthreads();
      int s = tid >> 1, half = tid & 1;
      const float* ep = enc_out + ((size_t)(b*128 + s))*512 + half*256;
      float acc = 0.f;
      #pragma unroll 4
      for (int k = 0; k < 64; ++k){
        f4v v = *(const f4v*)(ep + k*4);
        #pragma unroll
        for (int j = 0; j < 4; ++j) acc += qlds[half*256 + k*4 + j] * v[j];
      }
      part[tid] = acc;
      __syncthreads();
      if (tid < 128){
        float sc = (part[tid*2] + part[tid*2+1]) * 0.03125f;
        if (enc_mask[b*128 + tid] == 0) sc = -10000.0f;
        scbuf[tid] = sc; red[tid] = sc;
      }
      __syncthreads();
      for (int off = 64; off >= 1; off >>= 1){
        if (tid < off) red[tid] = fmaxf(red[tid], red[tid+off]);
        __syncthreads();
      }
      float mx = red[0];
      __syncthreads();
      if (tid < 128){ float e = __expf(scbuf[tid] - mx); wls[tid] = e; red[tid] = e; }
      __syncthreads();
      for (int off = 64; off >= 1; off >>= 1){
        if (tid < off) red[tid] += red[tid+off];
        __syncthreads();
      }
      float inv = 1.0f / red[0];
      float a0 = 0.f, a1 = 0.f;
      const float* eb = enc_out + (size_t)b*128*512;
      for (int s2 = 0; s2 < 128; ++s2){
        float wv = wls[s2];
        a0 += wv * eb[s2*512 + tid];
        a1 += wv * eb[s2*512 + 256 + tid];
      }
      {
        u16* so = stepin + ((t+1)&1)*32*1024 + b*1024;
        so[512 + tid]       = f2bf(a0*inv);
        so[512 + 256 + tid] = f2bf(a1*inv);
        int tok = tgt[b*64 + t + 1];
        so[tid]       = f2bf(embedding[(size_t)tok*512 + tid]);
        so[256 + tid] = f2bf(embedding[(size_t)tok*512 + 256 + tid]);
      }
    }
    grid.sync();
  }
}

// ---------------- projection: out[b][t][v] = X[t][b] @ proj_w.T + proj_b ----------------
__global__ __launch_bounds__(256) void proj_kernel(const u16* __restrict__ X,
                                                   const float* __restrict__ pw,
                                                   const float* __restrict__ pb,
                                                   float* __restrict__ out){
  __shared__ u16 As[128*64];
  __shared__ u16 Bs[128*64];
  int tid = threadIdx.x;
  int n0 = blockIdx.x*128, m0 = blockIdx.y*128;
  int w = tid>>6, l = tid&63;
  int wm = w & 1, wn = w >> 1;
  int lm = l & 15, lk8 = (l>>4)*8;
  f4v acc[4][4] = {};
  for (int kb = 0; kb < 16; ++kb){
    int k0 = kb*64;
    #pragma unroll
    for (int i = 0; i < 4; ++i){
      int c = tid*4 + i, row = c>>3, koff = (c&7)*8;
      *(s8v*)&As[row*64 + koff] = *(const s8v*)&X[(size_t)(m0+row)*1024 + k0 + koff];
      *(s8v*)&Bs[row*64 + koff] = cvt8(&pw[(size_t)(n0+row)*1024 + k0 + koff]);
    }
    __syncthreads();
    #pragma unroll
    for (int ki = 0; ki < 2; ++ki){
      s8v av[4], bv[4];
      #pragma unroll
      for (int mt = 0; mt < 4; ++mt) av[mt] = *(const s8v*)&As[(wm*64 + mt*16 + lm)*64 + ki*32 + lk8];
      #pragma unroll
      for (int nt = 0; nt < 4; ++nt) bv[nt] = *(const s8v*)&Bs[(wn*64 + nt*16 + lm)*64 + ki*32 + lk8];
      #pragma unroll
      for (int mt = 0; mt < 4; ++mt)
        #pragma unroll
        for (int nt = 0; nt < 4; ++nt)
          acc[mt][nt] = MFMA16(av[mt], bv[nt], acc[mt][nt]);
    }
    __syncthreads();
  }
  #pragma unroll
  for (int mt = 0; mt < 4; ++mt){
    #pragma unroll
    for (int r = 0; r < 4; ++r){
      int m = m0 + wm*64 + mt*16 + (l>>4)*4 + r;
      int tt = m >> 5, b = m & 31;                    // m = t*32 + b
      size_t obase = ((size_t)(b*64 + tt))*32000;
      #pragma unroll
      for (int nt = 0; nt < 4; ++nt){
        int nn = n0 + wn*64 + nt*16 + lm;
        out[obase + nn] = acc[mt][nt][r] + pb[nn];
      }
    }
  }
}

extern "C" void kernel_launch(void* const* d_in, const int* in_sizes, int n_in,
                              void* d_out, int out_size, void* d_ws, size_t ws_size,
                              hipStream_t stream){
  (void)in_sizes; (void)n_in; (void)out_size;
  const int*   tgt       = (const int*)d_in[0];
  const float* enc_out   = (const float*)d_in[2];
  const int*   enc_mask  = (const int*)d_in[3];
  const float* embedding = (const float*)d_in[4];
  const float* w_ih      = (const float*)d_in[5];
  const float* w_hh      = (const float*)d_in[6];
  const float* b_ih      = (const float*)d_in[7];
  const float* b_hh      = (const float*)d_in[8];
  const float* Wq        = (const float*)d_in[9];
  const float* Wk        = (const float*)d_in[10];
  const float* proj_w    = (const float*)d_in[11];
  const float* proj_b    = (const float*)d_in[12];

  // workspace: 6.6 MB core + 64 MB bf16 weight mirror + 4 KB barrier
  char* ws = (char*)d_ws;
  u16*  hbuf   = (u16*)  (ws + 0);                      // 524288 B
  float* cbuf  = (float*)(ws + 524288);                 // 524288 B  (zeroed region ends 1048576)
  u16*  stepin = (u16*)  (ws + 1048576);                // 131072 B
  u16*  xcur   = (u16*)  (ws + 1179648);                // 131072 B
  u16*  qbuf   = (u16*)  (ws + 1310720);                // 32768 B
  u16*  WqkT   = (u16*)  (ws + 1343488);                // 1048576 B
  u16*  Xbuf   = (u16*)  (ws + 2392064);                // 4194304 B -> core total 6586368 B
  u16*  wbf    = (u16*)  (ws + 6586368);                // 67108864 B (2 x [4][4096][1024] bf16)
  const size_t WS_CORE = 6586368;
  const size_t WBF_BYTES = 67108864;
  const size_t BAR_OFF = WS_CORE + WBF_BYTES;           // 73695232
  unsigned* barcnt = (unsigned*)(ws + BAR_OFF);
  unsigned* bargen = barcnt + 64;                        // separate cache line

  int mode = (ws_size >= BAR_OFF + 4096) ? 2 : ((ws_size >= WS_CORE + WBF_BYTES) ? 1 : 0);

  hipMemsetAsync(d_ws, 0, 1048576, stream);             // h0 + c0 = zeros
  wqk_kernel<<<128, 256, 0, stream>>>(Wq, Wk, WqkT);

  if (mode == 2){
    hipMemsetAsync(ws + BAR_OFF, 0, 4096, stream);      // barrier counter + generation = 0
    wcvt_kernel<<<dim3(8192, 2), 256, 0, stream>>>(w_ih, w_hh, wbf);
    void* args[] = { (void*)&tgt, (void*)&enc_out, (void*)&enc_mask, (void*)&embedding,
                     (void*)&wbf, (void*)&b_ih, (void*)&b_hh, (void*)&WqkT,
                     (void*)&hbuf, (void*)&cbuf, (void*)&stepin, (void*)&xcur,
                     (void*)&qbuf, (void*)&Xbuf, (void*)&barcnt, (void*)&bargen };
    hipLaunchCooperativeKernel((void*)decoder_kernel_bf2, dim3(256), dim3(256), args, 0, stream);
  } else if (mode == 1){
    wcvt_kernel<<<dim3(8192, 2), 256, 0, stream>>>(w_ih, w_hh, wbf);
    void* args[] = { (void*)&tgt, (void*)&enc_out, (void*)&enc_mask, (void*)&embedding,
                     (void*)&wbf, (void*)&b_ih, (void*)&b_hh, (void*)&WqkT,
                     (void*)&hbuf, (void*)&cbuf, (void*)&stepin, (void*)&xcur,
                     (void*)&qbuf, (void*)&Xbuf };
    hipLaunchCooperativeKernel((void*)decoder_kernel_bf, dim3(256), dim3(256), args, 0, stream);
  } else {
    // should not happen (round 3 proved ws_size >= WS_CORE + WBF_BYTES); bf path reuses f32 via wcvt
    wcvt_kernel<<<dim3(8192, 2), 256, 0, stream>>>(w_ih, w_hh, wbf);
    void* args[] = { (void*)&tgt, (void*)&enc_out, (void*)&enc_mask, (void*)&embedding,
                     (void*)&wbf, (void*)&b_ih, (void*)&b_hh, (void*)&WqkT,
                     (void*)&hbuf, (void*)&cbuf, (void*)&stepin, (void*)&xcur,
                     (void*)&qbuf, (void*)&Xbuf };
    hipLaunchCooperativeKernel((void*)decoder_kernel_bf, dim3(256), dim3(256), args, 0, stream);
  }

  dim3 pgrid(250, 16);
  proj_kernel<<<pgrid, 256, 0, stream>>>(Xbuf, proj_w, proj_b, (float*)d_out);
}